// Round 10
// baseline (277.728 us; speedup 1.0000x reference)
//
#include <hip/hip_runtime.h>
#include <hip/hip_bf16.h>
#include <cstddef>
#include <cstdint>

#define T_DIM 4096
#define B_DIM 8
#define N_DIM 256
#define H_DIM 512
#define NT_DIM 5

typedef __attribute__((ext_vector_type(8))) short short8;
typedef __attribute__((ext_vector_type(4))) float f32x4;

__device__ __forceinline__ short cvt_bf16(float f) {
  __hip_bfloat16 h = __float2bfloat16(f);
  union { __hip_bfloat16 h; short s; } u; u.h = h; return u.s;
}
__device__ __forceinline__ float bf2f(short s) {
  union { uint32_t u; float f; } v; v.u = ((uint32_t)(uint16_t)s) << 16;
  return v.f;
}

// async global->LDS, 16B/lane; LDS dest = wave-uniform base + lane*16
typedef __attribute__((address_space(1))) const void gvoid_t;
typedef __attribute__((address_space(3))) void lvoid_t;
__device__ __forceinline__ void gl_lds16(const void* g, void* lds_wave_base) {
  __builtin_amdgcn_global_load_lds((gvoid_t*)(uintptr_t)g,
                                   (lvoid_t*)(uint32_t)(uintptr_t)lds_wave_base,
                                   16, 0, 0);
}

#define MFMA16(a, b, c) __builtin_amdgcn_mfma_f32_16x16x32_bf16(a, b, c, 0, 0, 0)

// multi-slot GEMM descriptor: slot = blockIdx.z >> zlog, zz = blockIdx.z & mask
struct GP {
  const void* A[4];
  const short* B[4];
  void* C[4];
  const float* R[4];
  long long a_bs[4], b_bs[4], c_bs[4];
  int lda[4], ldb[4], ldc[4];
  int xlim[4], ylim[4];
};

// ---------------------------------------------------------------------------
// TN GEMM: C[m,n] = scale * sum_k A[m,k] * Bt[n,k]  (+ Res[m,n])
// 128x128 tile, 4 waves, BK=32, 3-deep counted-vmcnt pipelines (proven r7/r8).
// Per-slot geometry from GP; blocks outside (xlim,ylim) exit (slot merging).
// ---------------------------------------------------------------------------
template<typename TA, typename TC, bool ADD_RES>
__global__ __launch_bounds__(256)
void gemm_tn(GP p, int zlog, int K, float scale) {
  constexpr bool F32A = (sizeof(TA) == 4);
  constexpr int ASTR = F32A ? 40 : 32;
  constexpr int AB = 128 * ASTR * 2;
  constexpr int BB = 128 * 32 * 2;
  constexpr int HALF = AB + BB;
  constexpr int EPIB = 4 * 16 * 68 * 4;
  constexpr int BODYB = F32A ? (2 * AB + 3 * BB) : (3 * HALF);
  constexpr int SMEMB = BODYB > EPIB ? BODYB : EPIB;
  __shared__ __align__(16) char smem[SMEMB];

  const int dom = blockIdx.z >> zlog;
  const long long zz = blockIdx.z & ((1u << zlog) - 1u);
  if ((int)blockIdx.x >= p.xlim[dom] || (int)blockIdx.y >= p.ylim[dom]) return;

  const int lda = p.lda[dom], ldb = p.ldb[dom], ldc = p.ldc[dom];

  const int tid  = threadIdx.x;
  const int lane = tid & 63;
  const int wave = tid >> 6;
  const int wr   = (wave >> 1) * 64;
  const int wc   = (wave & 1) * 64;
  const int lrow = lane & 15;
  const int kgrp = lane >> 4;

  const TA*    Abase = (const TA*)p.A[dom] + zz * p.a_bs[dom] +
                       (long long)(blockIdx.x * 128) * lda;
  const short* Bbase = p.B[dom] + zz * p.b_bs[dom] +
                       (long long)(blockIdx.y * 128) * ldb;

  const int ch_r  = lane >> 2;
  const int swcol = ((lane & 3) ^ (ch_r & 3)) * 8;
  const int srow = tid >> 1;
  const int scol = (tid & 1) * 16;

  f32x4 acc[4][4] = {};
  f32x4 pv[4];

  auto stageA_bf16 = [&](int buf, int k0) {
    short* As = (short*)(smem + buf * HALF);
    #pragma unroll
    for (int i = 0; i < 2; ++i) {
      const int c = wave + 4 * i;
      gl_lds16((const short*)Abase + (long long)(c * 16 + ch_r) * lda + k0 + swcol,
               &As[c * 512]);
    }
  };
  auto stageB_bf16 = [&](int buf, int k0) {
    short* Bs = (short*)(smem + buf * HALF + AB);
    #pragma unroll
    for (int i = 0; i < 2; ++i) {
      const int c = wave + 4 * i;
      gl_lds16(Bbase + (long long)(c * 16 + ch_r) * ldb + k0 + swcol, &Bs[c * 512]);
    }
  };
  auto stageB_f32p = [&](int buf, int k0) {
    short* Bs = (short*)(smem + 2 * AB + buf * BB);
    #pragma unroll
    for (int i = 0; i < 2; ++i) {
      const int c = wave + 4 * i;
      gl_lds16(Bbase + (long long)(c * 16 + ch_r) * ldb + k0 + swcol, &Bs[c * 512]);
    }
  };
  auto loadA_f32 = [&](int k0) {
    const float* gp = (const float*)Abase + (long long)srow * lda + k0 + scol;
    pv[0] = *(const f32x4*)(gp + 0);
    pv[1] = *(const f32x4*)(gp + 4);
    pv[2] = *(const f32x4*)(gp + 8);
    pv[3] = *(const f32x4*)(gp + 12);
  };
  auto writeA_f32 = [&](int buf) {
    short* As = (short*)(smem + buf * AB);
    short8 s0, s1;
    #pragma unroll
    for (int e = 0; e < 4; ++e) {
      s0[e]     = cvt_bf16(pv[0][e]);
      s0[4 + e] = cvt_bf16(pv[1][e]);
      s1[e]     = cvt_bf16(pv[2][e]);
      s1[4 + e] = cvt_bf16(pv[3][e]);
    }
    *(short8*)&As[srow * ASTR + scol]     = s0;
    *(short8*)&As[srow * ASTR + scol + 8] = s1;
  };
  auto compute = [&](int abuf, int bbuf) {
    const short* As = (const short*)(smem + (F32A ? abuf * AB : abuf * HALF));
    const short* Bs = (const short*)(smem + (F32A ? 2 * AB + bbuf * BB
                                                  : bbuf * HALF + AB));
    short8 af[4], bfr[4];
    const int u = kgrp ^ (lrow & 3);
    #pragma unroll
    for (int i = 0; i < 4; ++i) {
      const int row = wr + i * 16 + lrow;
      if constexpr (F32A) af[i] = *(const short8*)&As[row * ASTR + kgrp * 8];
      else                af[i] = *(const short8*)&As[row * 32 + u * 8];
    }
    #pragma unroll
    for (int j = 0; j < 4; ++j) {
      const int row = wc + j * 16 + lrow;
      bfr[j] = *(const short8*)&Bs[row * 32 + u * 8];
    }
    #pragma unroll
    for (int i = 0; i < 4; ++i)
      #pragma unroll
      for (int j = 0; j < 4; ++j)
        acc[i][j] = MFMA16(af[i], bfr[j], acc[i][j]);
  };

  const int NT = K >> 5;
  if constexpr (F32A) {
    loadA_f32(0); writeA_f32(0);
    stageB_f32p(0, 0);
    if (NT > 1) stageB_f32p(1, 32);
    if (NT > 1) loadA_f32(32);
    for (int t = 0; t < NT; ++t) {
      asm volatile("s_waitcnt lgkmcnt(0)" ::: "memory");
      __builtin_amdgcn_sched_barrier(0);
      __builtin_amdgcn_s_barrier();       // A(t) visible; B rotate safe
      if (t + 2 < NT) stageB_f32p((t + 2) % 3, (t + 2) << 5);
      __builtin_amdgcn_sched_barrier(0);
      if (t + 2 < NT)      asm volatile("s_waitcnt vmcnt(8)" ::: "memory");
      else if (t + 1 < NT) asm volatile("s_waitcnt vmcnt(6)" ::: "memory");
      else                 asm volatile("s_waitcnt vmcnt(0)" ::: "memory");
      __builtin_amdgcn_sched_barrier(0);
      __builtin_amdgcn_s_barrier();       // B(t) staged for all waves
      __builtin_amdgcn_sched_barrier(0);
      compute(t & 1, t % 3);
      if (t + 1 < NT) writeA_f32((t + 1) & 1);
      if (t + 2 < NT) loadA_f32((t + 2) << 5);
    }
  } else {
    stageA_bf16(0, 0); stageB_bf16(0, 0);
    if (NT > 1) { stageA_bf16(1, 32); stageB_bf16(1, 32); }
    for (int t = 0; t < NT; ++t) {
      __builtin_amdgcn_s_barrier();
      if (t + 2 < NT) {
        stageA_bf16((t + 2) % 3, (t + 2) << 5);
        stageB_bf16((t + 2) % 3, (t + 2) << 5);
        __builtin_amdgcn_sched_barrier(0);
        asm volatile("s_waitcnt vmcnt(8)" ::: "memory");
      } else if (t + 1 < NT) {
        asm volatile("s_waitcnt vmcnt(4)" ::: "memory");
      } else {
        asm volatile("s_waitcnt vmcnt(0)" ::: "memory");
      }
      __builtin_amdgcn_sched_barrier(0);
      __builtin_amdgcn_s_barrier();
      __builtin_amdgcn_sched_barrier(0);
      compute(t % 3, t % 3);
    }
  }

  // ---- epilogue ----
  __syncthreads();
  float* myEp = (float*)smem + wave * (16 * 68);
  TC* Cd = (TC*)p.C[dom];
  const float* Res = p.R[dom];
  const long long cb = zz * p.c_bs[dom];
  const int gm = blockIdx.x * 128 + wr;
  const int gn = blockIdx.y * 128 + wc;
  const int er = lane >> 2;
  const int ec = (lane & 3) * 16;

  f32x4 resA[4], resB[4];
  if constexpr (ADD_RES) {
    const long long b0 = cb + (long long)(gm + er) * ldc + gn + ec;
    #pragma unroll
    for (int q = 0; q < 4; ++q) resA[q] = *(const f32x4*)&Res[b0 + q * 4];
  }

  #pragma unroll
  for (int i = 0; i < 4; ++i) {
    if constexpr (ADD_RES) {
      if (i < 3) {
        const long long bn = cb + (long long)(gm + (i + 1) * 16 + er) * ldc + gn + ec;
        #pragma unroll
        for (int q = 0; q < 4; ++q) resB[q] = *(const f32x4*)&Res[bn + q * 4];
      }
    }
    #pragma unroll
    for (int j = 0; j < 4; ++j)
      #pragma unroll
      for (int r = 0; r < 4; ++r)
        myEp[(kgrp * 4 + r) * 68 + j * 16 + lrow] = acc[i][j][r];
    float vals[16];
    #pragma unroll
    for (int q = 0; q < 4; ++q) {
      f32x4 t4 = *(const f32x4*)&myEp[er * 68 + ec + q * 4];
      vals[q * 4 + 0] = t4[0]; vals[q * 4 + 1] = t4[1];
      vals[q * 4 + 2] = t4[2]; vals[q * 4 + 3] = t4[3];
    }
    const int row_g = gm + i * 16 + er;
    const long long base = cb + (long long)row_g * ldc + gn + ec;
    if constexpr (sizeof(TC) == 2) {
      short8 s0, s1;
      #pragma unroll
      for (int e = 0; e < 8; ++e) {
        s0[e] = cvt_bf16(vals[e] * scale);
        s1[e] = cvt_bf16(vals[8 + e] * scale);
      }
      *(short8*)&Cd[base]     = s0;
      *(short8*)&Cd[base + 8] = s1;
    } else {
      #pragma unroll
      for (int q = 0; q < 4; ++q) {
        f32x4 o;
        #pragma unroll
        for (int e = 0; e < 4; ++e) o[e] = vals[q * 4 + e] * scale;
        if constexpr (ADD_RES) {
          #pragma unroll
          for (int e = 0; e < 4; ++e) o[e] += resA[q][e];
        }
        *(f32x4*)&Cd[base + q * 4] = o;
      }
    }
    if constexpr (ADD_RES) {
      #pragma unroll
      for (int q = 0; q < 4; ++q) resA[q] = resB[q];
    }
  }
}

// ---------------------------------------------------------------------------
// Merged prep kernel: role-dispatch on blockIdx.x.
//  [0,768):    raw f32->bf16 cvt of Wq,Wk,Wv (both domains) -> WT slots 0..5
//  [768,1280): transposed cvt of Wo (both)   -> WT slots 6,7
//  [1280,2304): action f32->bf16 (both domains)
//  [2304]:     task heads
// ---------------------------------------------------------------------------
struct PrepArgs {
  const float* w6[6];
  const float* w2[2];
  const float* av; const float* at;
  const float* vtask; const float* ttask;
  const float* vtw; const float* vtb;
  const float* ttw; const float* ttb;
  short* WT; short* Ac16v; short* Ac16t;
  float* out_vta; float* out_tta;
};

__global__ __launch_bounds__(256)
void prep_kernel(PrepArgs a) {
  __shared__ float tile[32][33];
  const long long WS = (long long)H_DIM * H_DIM;
  const int bx = blockIdx.x;
  const int tid = threadIdx.x;

  if (bx < 768) {               // raw weight cvt
    const int w = bx >> 7;
    const int blk = bx & 127;
    const float* src = a.w6[w];
    short* d = a.WT + (long long)w * WS;
    const int i = (blk * 256 + tid) * 8;
    f32x4 v0 = *(const f32x4*)(src + i);
    f32x4 v1 = *(const f32x4*)(src + i + 4);
    short8 o;
    #pragma unroll
    for (int e = 0; e < 4; ++e) { o[e] = cvt_bf16(v0[e]); o[4 + e] = cvt_bf16(v1[e]); }
    *(short8*)&d[i] = o;
  } else if (bx < 1280) {       // Wo transpose cvt
    const int r = bx - 768;
    const int w = r >> 8;
    const int rem = r & 255;
    const int n0 = (rem >> 4) * 32, k0 = (rem & 15) * 32;
    const float* src = a.w2[w];
    short* d = a.WT + (long long)(6 + w) * WS;
    const int tx = tid & 31, ty = tid >> 5;
    #pragma unroll
    for (int i = 0; i < 4; ++i)
      tile[ty + 8 * i][tx] = src[(long long)(k0 + ty + 8 * i) * H_DIM + n0 + tx];
    __syncthreads();
    #pragma unroll
    for (int i = 0; i < 4; ++i)
      d[(long long)(n0 + ty + 8 * i) * H_DIM + k0 + tx] = cvt_bf16(tile[tx][ty + 8 * i]);
  } else if (bx < 2304) {       // action cvt
    const int r = bx - 1280;
    const int dom = r >> 9;
    const int blk = r & 511;
    const float* src = dom ? a.at : a.av;
    short* d = dom ? a.Ac16t : a.Ac16v;
    const int i = (blk * 256 + tid) * 8;
    f32x4 v0 = *(const f32x4*)(src + i);
    f32x4 v1 = *(const f32x4*)(src + i + 4);
    short8 o;
    #pragma unroll
    for (int e = 0; e < 4; ++e) { o[e] = cvt_bf16(v0[e]); o[4 + e] = cvt_bf16(v1[e]); }
    *(short8*)&d[i] = o;
  } else {                      // task heads
    const int wave = tid >> 6;
    const int lane = tid & 63;
    for (int g = wave; g < 16; g += 4) {
      const int dom = g >> 3;
      const int b = g & 7;
      const float* task = dom ? a.ttask : a.vtask;
      const float* tw   = dom ? a.ttw : a.vtw;
      const float  tb   = (dom ? a.ttb : a.vtb)[0];
      float* o = dom ? a.out_tta : a.out_vta;
      for (int k = 0; k < NT_DIM; ++k) {
        const float* row = task + ((long long)k * B_DIM + b) * H_DIM;
        float s = 0.f;
        for (int c = lane; c < H_DIM; c += 64) s += row[c] * tw[c];
        #pragma unroll
        for (int d = 32; d > 0; d >>= 1) s += __shfl_xor(s, d);
        if (lane == 0) o[k * B_DIM + b] = s + tb;
      }
    }
  }
}

// ---------------------------------------------------------------------------
// Fused: combine + masked softmax + bf16 attn + nomask transpose (r6 proven)
// ---------------------------------------------------------------------------
__global__ __launch_bounds__(256)
void softmax_fused(const short* __restrict__ Lv, const short* __restrict__ Lt,
                   const int* __restrict__ vmask, const int* __restrict__ tmask,
                   const float* __restrict__ vaw, const float* __restrict__ taw,
                   short* __restrict__ Av, short* __restrict__ At,
                   float* __restrict__ Onm_v, float* __restrict__ Onm_t) {
  __shared__ float tile[16 * 260];
  __shared__ int msk[2][256];
  const int tid = threadIdx.x;
  const int b = blockIdx.y, t0 = blockIdx.x * 16;
  const int r = tid >> 4, seg = tid & 15;
  msk[0][tid] = vmask[b * 256 + tid];
  msk[1][tid] = tmask[b * 256 + tid];
  __syncthreads();
  const float sv = 1.f / (1.f + __expf(-vaw[0]));
  const float st = 1.f / (1.f + __expf(-taw[0]));
  const long long off = ((long long)b * T_DIM + t0 + r) * N_DIM + seg * 16;

  short8 lv0 = *(const short8*)&Lv[off];
  short8 lv1 = *(const short8*)&Lv[off + 8];
  short8 lt0 = *(const short8*)&Lt[off];
  short8 lt1 = *(const short8*)&Lt[off + 8];
  float cv[16], ct[16];
  #pragma unroll
  for (int i = 0; i < 8; ++i) {
    float a0 = bf2f(lv0[i]), b0 = bf2f(lt0[i]);
    float a1 = bf2f(lv1[i]), b1 = bf2f(lt1[i]);
    cv[i]     = a0 + sv * b0;  ct[i]     = b0 + st * a0;
    cv[8 + i] = a1 + sv * b1;  ct[8 + i] = b1 + st * a1;
  }

#define EMIT_DOMAIN(CVAL, DI, AOUT, ONM) do {                                   \
    const int4 mA = *(const int4*)&msk[DI][seg * 16 + 0];                       \
    const int4 mB = *(const int4*)&msk[DI][seg * 16 + 4];                       \
    const int4 mC = *(const int4*)&msk[DI][seg * 16 + 8];                       \
    const int4 mD = *(const int4*)&msk[DI][seg * 16 + 12];                      \
    const int mk[16] = {mA.x, mA.y, mA.z, mA.w, mB.x, mB.y, mB.z, mB.w,         \
                        mC.x, mC.y, mC.z, mC.w, mD.x, mD.y, mD.z, mD.w};        \
    float mx = -3.4e38f;                                                        \
    _Pragma("unroll")                                                           \
    for (int q = 0; q < 16; ++q) if (mk[q] > 0) mx = fmaxf(mx, CVAL[q]);        \
    _Pragma("unroll")                                                           \
    for (int sh = 1; sh < 16; sh <<= 1) mx = fmaxf(mx, __shfl_xor(mx, sh));     \
    float ev[16]; float ssum = 0.f;                                             \
    _Pragma("unroll")                                                           \
    for (int q = 0; q < 16; ++q) {                                              \
      ev[q] = (mk[q] > 0) ? __expf(CVAL[q] - mx) : 0.f; ssum += ev[q];          \
    }                                                                           \
    _Pragma("unroll")                                                           \
    for (int sh = 1; sh < 16; sh <<= 1) ssum += __shfl_xor(ssum, sh);           \
    const float inv = 1.f / ssum;                                               \
    short8 o0, o1;                                                              \
    _Pragma("unroll")                                                           \
    for (int q = 0; q < 8; ++q) {                                               \
      o0[q] = cvt_bf16(ev[q] * inv); o1[q] = cvt_bf16(ev[8 + q] * inv);         \
    }                                                                           \
    *(short8*)&AOUT[off] = o0; *(short8*)&AOUT[off + 8] = o1;                   \
    _Pragma("unroll")                                                           \
    for (int q = 0; q < 4; ++q) {                                               \
      f32x4 tv; tv[0] = CVAL[q * 4]; tv[1] = CVAL[q * 4 + 1];                   \
      tv[2] = CVAL[q * 4 + 2]; tv[3] = CVAL[q * 4 + 3];                         \
      *(f32x4*)&tile[r * 260 + seg * 16 + q * 4] = tv;                          \
    }                                                                           \
    __syncthreads();                                                            \
    {                                                                           \
      float* obase = &ONM[((long long)b * N_DIM + tid) * T_DIM + t0];           \
      _Pragma("unroll")                                                         \
      for (int g = 0; g < 4; ++g) {                                             \
        f32x4 wv;                                                               \
        wv[0] = tile[(4 * g + 0) * 260 + tid];                                  \
        wv[1] = tile[(4 * g + 1) * 260 + tid];                                  \
        wv[2] = tile[(4 * g + 2) * 260 + tid];                                  \
        wv[3] = tile[(4 * g + 3) * 260 + tid];                                  \
        *(f32x4*)&obase[4 * g] = wv;                                            \
      }                                                                         \
    }                                                                           \
    __syncthreads();                                                            \
  } while (0)

  EMIT_DOMAIN(cv, 0, Av, Onm_v);
  EMIT_DOMAIN(ct, 1, At, Onm_t);
#undef EMIT_DOMAIN
}

// ---------------------------------------------------------------------------
extern "C" void kernel_launch(void* const* d_in, const int* in_sizes, int n_in,
                              void* d_out, int out_size, void* d_ws, size_t ws_size,
                              hipStream_t stream) {
  const float* v_action = (const float*)d_in[0];
  const float* v_frame  = (const float*)d_in[1];
  const float* v_task   = (const float*)d_in[2];
  const int*   v_mask   = (const int*)d_in[3];
  const float* t_action = (const float*)d_in[4];
  const float* t_frame  = (const float*)d_in[5];
  const float* t_task   = (const float*)d_in[6];
  const int*   t_mask   = (const int*)d_in[7];
  const float* v_aw = (const float*)d_in[16];
  const float* t_aw = (const float*)d_in[17];
  const float* v_tw = (const float*)d_in[18];
  const float* v_tb = (const float*)d_in[19];
  const float* t_tw = (const float*)d_in[20];
  const float* t_tb = (const float*)d_in[21];

  const long long TBH = (long long)T_DIM * B_DIM * H_DIM;
  const long long BTN = (long long)B_DIM * T_DIM * N_DIM;
  const long long WS  = (long long)H_DIM * H_DIM;     // 262144

  float* out = (float*)d_out;
  float* out_v   = out;
  float* out_t   = out + TBH;
  float* out_vnm = out + 2 * TBH;
  float* out_tnm = out + 2 * TBH + BTN;
  float* out_vta = out + 2 * TBH + 2 * BTN;
  float* out_tta = out_vta + NT_DIM * B_DIM;

  char* w = (char*)d_ws;
  auto alloc = [&](long long bytes) {
    char* p = w; w += (bytes + 255) & ~255LL; return p;
  };
  // WT slots: 0 WQv,1 WKv,2 WVv,3 WQt,4 WKt,5 WVt (raw), 6 WoTv,7 WoTt (trans)
  short* WT    = (short*)alloc(8 * WS * 2);
  short* Mv    = (short*)alloc(WS * 2);
  short* Mt    = (short*)alloc(WS * 2);
  short* PTv   = (short*)alloc(WS * 2);
  short* PTt   = (short*)alloc(WS * 2);
  short* Ac16v = (short*)alloc(1048576LL * 2);
  short* Ac16t = (short*)alloc(1048576LL * 2);
  short* KWTv  = (short*)alloc(8LL * 131072 * 2);  // [b][n][f]
  short* KWTt  = (short*)alloc(8LL * 131072 * 2);
  short* VWTv  = (short*)alloc(8LL * 131072 * 2);  // [b][g][n]
  short* VWTt  = (short*)alloc(8LL * 131072 * 2);
  short* Av    = (short*)alloc(BTN * 2);
  short* At    = (short*)alloc(BTN * 2);
  short* Lv    = (short*)alloc(BTN * 2);
  short* Lt    = (short*)alloc(BTN * 2);

  const float rsq = 0.044194173824159216f;  // 1/sqrt(512)

  // 1. merged prep: weight cvts + action cvt + task heads
  {
    PrepArgs a;
    a.w6[0] = (const float*)d_in[8];  a.w6[1] = (const float*)d_in[9];
    a.w6[2] = (const float*)d_in[10]; a.w6[3] = (const float*)d_in[12];
    a.w6[4] = (const float*)d_in[13]; a.w6[5] = (const float*)d_in[14];
    a.w2[0] = (const float*)d_in[11]; a.w2[1] = (const float*)d_in[15];
    a.av = v_action; a.at = t_action;
    a.vtask = v_task; a.ttask = t_task;
    a.vtw = v_tw; a.vtb = v_tb; a.ttw = t_tw; a.ttb = t_tb;
    a.WT = WT; a.Ac16v = Ac16v; a.Ac16t = Ac16t;
    a.out_vta = out_vta; a.out_tta = out_tta;
    prep_kernel<<<dim3(2305), dim3(256), 0, stream>>>(a);
  }

  // 2. M = Wq@Wk^T and PT = WoT@Wv (4 slots, zlog=0 -> dom=z)
  {
    GP p = {};
    const short* As[4] = {WT + 0 * WS, WT + 3 * WS, WT + 6 * WS, WT + 7 * WS};
    const short* Bs[4] = {WT + 1 * WS, WT + 4 * WS, WT + 2 * WS, WT + 5 * WS};
    short* Cs[4] = {Mv, Mt, PTv, PTt};
    for (int s = 0; s < 4; ++s) {
      p.A[s] = As[s]; p.B[s] = Bs[s]; p.C[s] = Cs[s]; p.R[s] = nullptr;
      p.a_bs[s] = 0; p.b_bs[s] = 0; p.c_bs[s] = 0;
      p.lda[s] = H_DIM; p.ldb[s] = H_DIM; p.ldc[s] = H_DIM;
      p.xlim[s] = 4; p.ylim[s] = 4;
    }
    gemm_tn<short, short, false><<<dim3(4, 4, 4), dim3(256), 0, stream>>>(
        p, 0, 512, 1.f);
  }

  // 3. KWT (slots 0,1) + VWT (slots 2,3) in ONE launch (zlog=3, z=slot*8+b)
  {
    GP p = {};
    // KWT[b][n][f] = action @ M^T : M=256 (xlim 2), N=512 (ylim 4)
    p.A[0] = Ac16v; p.B[0] = Mv; p.C[0] = KWTv;
    p.A[1] = Ac16t; p.B[1] = Mt; p.C[1] = KWTt;
    for (int s = 0; s < 2; ++s) {
      p.a_bs[s] = 512; p.lda[s] = B_DIM * H_DIM;
      p.b_bs[s] = 0;   p.ldb[s] = H_DIM;
      p.c_bs[s] = 131072; p.ldc[s] = H_DIM;
      p.xlim[s] = 2; p.ylim[s] = 4; p.R[s] = nullptr;
    }
    // VWT[b][g][n] = PT @ action^T : M=512 (xlim 4), N=256 (ylim 2)
    p.A[2] = PTv; p.B[2] = Ac16v; p.C[2] = VWTv;
    p.A[3] = PTt; p.B[3] = Ac16t; p.C[3] = VWTt;
    for (int s = 2; s < 4; ++s) {
      p.a_bs[s] = 0;   p.lda[s] = H_DIM;
      p.b_bs[s] = 512; p.ldb[s] = B_DIM * H_DIM;
      p.c_bs[s] = 131072; p.ldc[s] = N_DIM;
      p.xlim[s] = 4; p.ylim[s] = 2; p.R[s] = nullptr;
    }
    gemm_tn<short, short, false><<<dim3(4, 4, 32), dim3(256), 0, stream>>>(
        p, 3, 512, 1.f);
  }

  // 4. logits (bf16) [B,T,N] = frame @ KWT^T  (f32-A path; z = dom*8+b)
  {
    GP p = {};
    p.A[0] = v_frame; p.B[0] = KWTv; p.C[0] = Lv;
    p.A[1] = t_frame; p.B[1] = KWTt; p.C[1] = Lt;
    for (int s = 0; s < 2; ++s) {
      p.a_bs[s] = 512; p.lda[s] = B_DIM * H_DIM;
      p.b_bs[s] = 131072; p.ldb[s] = H_DIM;
      p.c_bs[s] = (long long)T_DIM * N_DIM; p.ldc[s] = N_DIM;
      p.xlim[s] = 32; p.ylim[s] = 2; p.R[s] = nullptr;
    }
    gemm_tn<float, short, false><<<dim3(32, 2, 16), dim3(256), 0, stream>>>(
        p, 3, 512, rsq);
  }

  // 5. fused combine + softmax + nomask-transpose
  softmax_fused<<<dim3(T_DIM / 16, B_DIM), dim3(256), 0, stream>>>(
      Lv, Lt, v_mask, t_mask, v_aw, t_aw, Av, At, out_vnm, out_tnm);

  // 6. out = attn @ VW + frame  (K=256)
  {
    GP p = {};
    p.A[0] = Av; p.B[0] = VWTv; p.C[0] = out_v; p.R[0] = v_frame;
    p.A[1] = At; p.B[1] = VWTt; p.C[1] = out_t; p.R[1] = t_frame;
    for (int s = 0; s < 2; ++s) {
      p.a_bs[s] = (long long)T_DIM * N_DIM; p.lda[s] = N_DIM;
      p.b_bs[s] = 131072; p.ldb[s] = N_DIM;
      p.c_bs[s] = 512; p.ldc[s] = B_DIM * H_DIM;
      p.xlim[s] = 32; p.ylim[s] = 4;
    }
    gemm_tn<short, float, true><<<dim3(32, 4, 16), dim3(256), 0, stream>>>(
        p, 3, 256, 1.f);
  }
}

// Round 11
// 244.492 us; speedup vs baseline: 1.1359x; 1.1359x over previous
//
#include <hip/hip_runtime.h>
#include <hip/hip_bf16.h>
#include <cstddef>
#include <cstdint>

#define T_DIM 4096
#define B_DIM 8
#define N_DIM 256
#define H_DIM 512
#define NT_DIM 5

typedef __attribute__((ext_vector_type(8))) short short8;
typedef __attribute__((ext_vector_type(4))) float f32x4;

__device__ __forceinline__ short cvt_bf16(float f) {
  __hip_bfloat16 h = __float2bfloat16(f);
  union { __hip_bfloat16 h; short s; } u; u.h = h; return u.s;
}
__device__ __forceinline__ float bf2f(short s) {
  union { uint32_t u; float f; } v; v.u = ((uint32_t)(uint16_t)s) << 16;
  return v.f;
}

// async global->LDS, 16B/lane; LDS dest = wave-uniform base + lane*16
typedef __attribute__((address_space(1))) const void gvoid_t;
typedef __attribute__((address_space(3))) void lvoid_t;
__device__ __forceinline__ void gl_lds16(const void* g, void* lds_wave_base) {
  __builtin_amdgcn_global_load_lds((gvoid_t*)(uintptr_t)g,
                                   (lvoid_t*)(uint32_t)(uintptr_t)lds_wave_base,
                                   16, 0, 0);
}

#define MFMA16(a, b, c) __builtin_amdgcn_mfma_f32_16x16x32_bf16(a, b, c, 0, 0, 0)

// multi-slot pointer set: slot = z >> zlog, zz = z & mask
struct GP {
  const void* A[4];
  const short* B[4];
  void* C[4];
  const float* R[4];
};

// ---------------------------------------------------------------------------
// TN GEMM: C[m,n] = scale * sum_k A[m,k] * Bt[n,k]  (+ Res[m,n])
// 128x128 tile, 4 waves, BK=32, 3-deep counted-vmcnt pipelines (proven r7/r8).
// FLAT=true: 1D grid with XCD-chunk swizzle (T1), logical order y-fastest so
// A-panel-sharing blocks land on the same XCD's L2.
// ---------------------------------------------------------------------------
template<typename TA, typename TC, bool ADD_RES, bool FLAT = false>
__global__ __launch_bounds__(256)
void gemm_tn(GP p, int zlog, long long a_bs, int lda,
             long long b_bs, int ldb, long long c_bs, int ldc,
             int K, float scale, int NX = 1, int NY = 1) {
  constexpr bool F32A = (sizeof(TA) == 4);
  constexpr int ASTR = F32A ? 40 : 32;
  constexpr int AB = 128 * ASTR * 2;
  constexpr int BB = 128 * 32 * 2;
  constexpr int HALF = AB + BB;
  constexpr int EPIB = 4 * 16 * 68 * 4;
  constexpr int BODYB = F32A ? (2 * AB + 3 * BB) : (3 * HALF);
  constexpr int SMEMB = BODYB > EPIB ? BODYB : EPIB;
  __shared__ __align__(16) char smem[SMEMB];

  int bx, by, zidx;
  if constexpr (FLAT) {
    const int q = gridDim.x >> 3;                       // grid %8 == 0
    const int lid = (blockIdx.x & 7) * q + (blockIdx.x >> 3);
    zidx = lid / (NX * NY);
    const int rem = lid - zidx * (NX * NY);
    bx = rem / NY;
    by = rem - bx * NY;
  } else {
    bx = blockIdx.x; by = blockIdx.y; zidx = blockIdx.z;
  }

  const int dom = zidx >> zlog;
  const long long zz = zidx & ((1u << zlog) - 1u);

  const int tid  = threadIdx.x;
  const int lane = tid & 63;
  const int wave = tid >> 6;
  const int wr   = (wave >> 1) * 64;
  const int wc   = (wave & 1) * 64;
  const int lrow = lane & 15;
  const int kgrp = lane >> 4;

  const TA*    Abase = (const TA*)p.A[dom] + zz * a_bs + (long long)(bx * 128) * lda;
  const short* Bbase = p.B[dom] + zz * b_bs + (long long)(by * 128) * ldb;

  const int ch_r  = lane >> 2;
  const int swcol = ((lane & 3) ^ (ch_r & 3)) * 8;
  const int srow = tid >> 1;
  const int scol = (tid & 1) * 16;

  f32x4 acc[4][4] = {};
  f32x4 pv[4];

  auto stageA_bf16 = [&](int buf, int k0) {
    short* As = (short*)(smem + buf * HALF);
    #pragma unroll
    for (int i = 0; i < 2; ++i) {
      const int c = wave + 4 * i;
      gl_lds16((const short*)Abase + (long long)(c * 16 + ch_r) * lda + k0 + swcol,
               &As[c * 512]);
    }
  };
  auto stageB_bf16 = [&](int buf, int k0) {
    short* Bs = (short*)(smem + buf * HALF + AB);
    #pragma unroll
    for (int i = 0; i < 2; ++i) {
      const int c = wave + 4 * i;
      gl_lds16(Bbase + (long long)(c * 16 + ch_r) * ldb + k0 + swcol, &Bs[c * 512]);
    }
  };
  auto stageB_f32p = [&](int buf, int k0) {
    short* Bs = (short*)(smem + 2 * AB + buf * BB);
    #pragma unroll
    for (int i = 0; i < 2; ++i) {
      const int c = wave + 4 * i;
      gl_lds16(Bbase + (long long)(c * 16 + ch_r) * ldb + k0 + swcol, &Bs[c * 512]);
    }
  };
  auto loadA_f32 = [&](int k0) {
    const float* gp = (const float*)Abase + (long long)srow * lda + k0 + scol;
    pv[0] = *(const f32x4*)(gp + 0);
    pv[1] = *(const f32x4*)(gp + 4);
    pv[2] = *(const f32x4*)(gp + 8);
    pv[3] = *(const f32x4*)(gp + 12);
  };
  auto writeA_f32 = [&](int buf) {
    short* As = (short*)(smem + buf * AB);
    short8 s0, s1;
    #pragma unroll
    for (int e = 0; e < 4; ++e) {
      s0[e]     = cvt_bf16(pv[0][e]);
      s0[4 + e] = cvt_bf16(pv[1][e]);
      s1[e]     = cvt_bf16(pv[2][e]);
      s1[4 + e] = cvt_bf16(pv[3][e]);
    }
    *(short8*)&As[srow * ASTR + scol]     = s0;
    *(short8*)&As[srow * ASTR + scol + 8] = s1;
  };
  auto compute = [&](int abuf, int bbuf) {
    const short* As = (const short*)(smem + (F32A ? abuf * AB : abuf * HALF));
    const short* Bs = (const short*)(smem + (F32A ? 2 * AB + bbuf * BB
                                                  : bbuf * HALF + AB));
    short8 af[4], bfr[4];
    const int u = kgrp ^ (lrow & 3);
    #pragma unroll
    for (int i = 0; i < 4; ++i) {
      const int row = wr + i * 16 + lrow;
      if constexpr (F32A) af[i] = *(const short8*)&As[row * ASTR + kgrp * 8];
      else                af[i] = *(const short8*)&As[row * 32 + u * 8];
    }
    #pragma unroll
    for (int j = 0; j < 4; ++j) {
      const int row = wc + j * 16 + lrow;
      bfr[j] = *(const short8*)&Bs[row * 32 + u * 8];
    }
    #pragma unroll
    for (int i = 0; i < 4; ++i)
      #pragma unroll
      for (int j = 0; j < 4; ++j)
        acc[i][j] = MFMA16(af[i], bfr[j], acc[i][j]);
  };

  const int NT = K >> 5;
  if constexpr (F32A) {
    loadA_f32(0); writeA_f32(0);
    stageB_f32p(0, 0);
    if (NT > 1) stageB_f32p(1, 32);
    if (NT > 1) loadA_f32(32);
    for (int t = 0; t < NT; ++t) {
      asm volatile("s_waitcnt lgkmcnt(0)" ::: "memory");
      __builtin_amdgcn_sched_barrier(0);
      __builtin_amdgcn_s_barrier();       // A(t) visible; B rotate safe
      if (t + 2 < NT) stageB_f32p((t + 2) % 3, (t + 2) << 5);
      __builtin_amdgcn_sched_barrier(0);
      if (t + 2 < NT)      asm volatile("s_waitcnt vmcnt(8)" ::: "memory");
      else if (t + 1 < NT) asm volatile("s_waitcnt vmcnt(6)" ::: "memory");
      else                 asm volatile("s_waitcnt vmcnt(0)" ::: "memory");
      __builtin_amdgcn_sched_barrier(0);
      __builtin_amdgcn_s_barrier();       // B(t) staged for all waves
      __builtin_amdgcn_sched_barrier(0);
      compute(t & 1, t % 3);
      if (t + 1 < NT) writeA_f32((t + 1) & 1);
      if (t + 2 < NT) loadA_f32((t + 2) << 5);
    }
  } else {
    stageA_bf16(0, 0); stageB_bf16(0, 0);
    if (NT > 1) { stageA_bf16(1, 32); stageB_bf16(1, 32); }
    for (int t = 0; t < NT; ++t) {
      __builtin_amdgcn_s_barrier();
      if (t + 2 < NT) {
        stageA_bf16((t + 2) % 3, (t + 2) << 5);
        stageB_bf16((t + 2) % 3, (t + 2) << 5);
        __builtin_amdgcn_sched_barrier(0);
        asm volatile("s_waitcnt vmcnt(8)" ::: "memory");
      } else if (t + 1 < NT) {
        asm volatile("s_waitcnt vmcnt(4)" ::: "memory");
      } else {
        asm volatile("s_waitcnt vmcnt(0)" ::: "memory");
      }
      __builtin_amdgcn_sched_barrier(0);
      __builtin_amdgcn_s_barrier();
      __builtin_amdgcn_sched_barrier(0);
      compute(t % 3, t % 3);
    }
  }

  // ---- epilogue ----
  __syncthreads();
  float* myEp = (float*)smem + wave * (16 * 68);
  TC* Cd = (TC*)p.C[dom];
  const float* Res = p.R[dom];
  const long long cb = zz * c_bs;
  const int gm = bx * 128 + wr;
  const int gn = by * 128 + wc;
  const int er = lane >> 2;
  const int ec = (lane & 3) * 16;

  f32x4 resA[4], resB[4];
  if constexpr (ADD_RES) {
    const long long b0 = cb + (long long)(gm + er) * ldc + gn + ec;
    #pragma unroll
    for (int q = 0; q < 4; ++q) resA[q] = *(const f32x4*)&Res[b0 + q * 4];
  }

  #pragma unroll
  for (int i = 0; i < 4; ++i) {
    if constexpr (ADD_RES) {
      if (i < 3) {
        const long long bn = cb + (long long)(gm + (i + 1) * 16 + er) * ldc + gn + ec;
        #pragma unroll
        for (int q = 0; q < 4; ++q) resB[q] = *(const f32x4*)&Res[bn + q * 4];
      }
    }
    #pragma unroll
    for (int j = 0; j < 4; ++j)
      #pragma unroll
      for (int r = 0; r < 4; ++r)
        myEp[(kgrp * 4 + r) * 68 + j * 16 + lrow] = acc[i][j][r];
    float vals[16];
    #pragma unroll
    for (int q = 0; q < 4; ++q) {
      f32x4 t4 = *(const f32x4*)&myEp[er * 68 + ec + q * 4];
      vals[q * 4 + 0] = t4[0]; vals[q * 4 + 1] = t4[1];
      vals[q * 4 + 2] = t4[2]; vals[q * 4 + 3] = t4[3];
    }
    const int row_g = gm + i * 16 + er;
    const long long base = cb + (long long)row_g * ldc + gn + ec;
    if constexpr (sizeof(TC) == 2) {
      short8 s0, s1;
      #pragma unroll
      for (int e = 0; e < 8; ++e) {
        s0[e] = cvt_bf16(vals[e] * scale);
        s1[e] = cvt_bf16(vals[8 + e] * scale);
      }
      *(short8*)&Cd[base]     = s0;
      *(short8*)&Cd[base + 8] = s1;
    } else {
      #pragma unroll
      for (int q = 0; q < 4; ++q) {
        f32x4 o;
        #pragma unroll
        for (int e = 0; e < 4; ++e) o[e] = vals[q * 4 + e] * scale;
        if constexpr (ADD_RES) {
          #pragma unroll
          for (int e = 0; e < 4; ++e) o[e] += resA[q][e];
        }
        *(f32x4*)&Cd[base + q * 4] = o;
      }
    }
    if constexpr (ADD_RES) {
      #pragma unroll
      for (int q = 0; q < 4; ++q) resA[q] = resB[q];
    }
  }
}

// ---------------------------------------------------------------------------
// Raw f32->bf16 copy of 6 weight matrices (Wq,Wk,Wv both domains)
// ---------------------------------------------------------------------------
struct W6 { const float* p[6]; };

__global__ __launch_bounds__(256)
void rawcvt_kernel(W6 s, short* __restrict__ dst) {
  const int w = blockIdx.y;
  const float* src = s.p[w];
  short* d = dst + (long long)w * H_DIM * H_DIM;
  const int i = (blockIdx.x * 256 + threadIdx.x) * 8;   // grid.x = 128
  f32x4 v0 = *(const f32x4*)(src + i);
  f32x4 v1 = *(const f32x4*)(src + i + 4);
  short8 o;
  #pragma unroll
  for (int e = 0; e < 4; ++e) { o[e] = cvt_bf16(v0[e]); o[4 + e] = cvt_bf16(v1[e]); }
  *(short8*)&d[i] = o;
}

// ---------------------------------------------------------------------------
// Transposed cvt for Wo (2 matrices): WoT[n][k] = bf16(Wo[k][n])
// ---------------------------------------------------------------------------
struct W2 { const float* p[2]; };

__global__ __launch_bounds__(256)
void wtrans_kernel(W2 s, short* __restrict__ dst) {
  __shared__ float tile[32][33];
  const int w = blockIdx.z;
  const float* src = s.p[w];
  short* d = dst + (long long)w * H_DIM * H_DIM;
  const int tx = threadIdx.x, ty = threadIdx.y;
  const int n0 = blockIdx.x * 32, k0 = blockIdx.y * 32;
  #pragma unroll
  for (int i = 0; i < 4; ++i)
    tile[ty + 8 * i][tx] = src[(long long)(k0 + ty + 8 * i) * H_DIM + n0 + tx];
  __syncthreads();
  #pragma unroll
  for (int i = 0; i < 4; ++i)
    d[(long long)(n0 + ty + 8 * i) * H_DIM + k0 + tx] = cvt_bf16(tile[tx][ty + 8 * i]);
}

// ---------------------------------------------------------------------------
// action f32 -> bf16 (layout preserved), both domains
// ---------------------------------------------------------------------------
__global__ __launch_bounds__(256)
void ac16_kernel(const float* __restrict__ av, const float* __restrict__ at,
                 short* __restrict__ ov, short* __restrict__ ot) {
  const int dom = blockIdx.y;
  const float* src = dom ? at : av;
  short* d = dom ? ot : ov;
  const int i = (blockIdx.x * 256 + threadIdx.x) * 8;   // grid.x = 512
  f32x4 v0 = *(const f32x4*)(src + i);
  f32x4 v1 = *(const f32x4*)(src + i + 4);
  short8 o;
  #pragma unroll
  for (int e = 0; e < 4; ++e) { o[e] = cvt_bf16(v0[e]); o[4 + e] = cvt_bf16(v1[e]); }
  *(short8*)&d[i] = o;
}

// ---------------------------------------------------------------------------
// Fused: combine + masked softmax + bf16 attn + nomask transpose (r6 proven)
// ---------------------------------------------------------------------------
__global__ __launch_bounds__(256)
void softmax_fused(const short* __restrict__ Lv, const short* __restrict__ Lt,
                   const int* __restrict__ vmask, const int* __restrict__ tmask,
                   const float* __restrict__ vaw, const float* __restrict__ taw,
                   short* __restrict__ Av, short* __restrict__ At,
                   float* __restrict__ Onm_v, float* __restrict__ Onm_t) {
  __shared__ float tile[16 * 260];
  __shared__ int msk[2][256];
  const int tid = threadIdx.x;
  const int b = blockIdx.y, t0 = blockIdx.x * 16;
  const int r = tid >> 4, seg = tid & 15;
  msk[0][tid] = vmask[b * 256 + tid];
  msk[1][tid] = tmask[b * 256 + tid];
  __syncthreads();
  const float sv = 1.f / (1.f + __expf(-vaw[0]));
  const float st = 1.f / (1.f + __expf(-taw[0]));
  const long long off = ((long long)b * T_DIM + t0 + r) * N_DIM + seg * 16;

  short8 lv0 = *(const short8*)&Lv[off];
  short8 lv1 = *(const short8*)&Lv[off + 8];
  short8 lt0 = *(const short8*)&Lt[off];
  short8 lt1 = *(const short8*)&Lt[off + 8];
  float cv[16], ct[16];
  #pragma unroll
  for (int i = 0; i < 8; ++i) {
    float a0 = bf2f(lv0[i]), b0 = bf2f(lt0[i]);
    float a1 = bf2f(lv1[i]), b1 = bf2f(lt1[i]);
    cv[i]     = a0 + sv * b0;  ct[i]     = b0 + st * a0;
    cv[8 + i] = a1 + sv * b1;  ct[8 + i] = b1 + st * a1;
  }

#define EMIT_DOMAIN(CVAL, DI, AOUT, ONM) do {                                   \
    const int4 mA = *(const int4*)&msk[DI][seg * 16 + 0];                       \
    const int4 mB = *(const int4*)&msk[DI][seg * 16 + 4];                       \
    const int4 mC = *(const int4*)&msk[DI][seg * 16 + 8];                       \
    const int4 mD = *(const int4*)&msk[DI][seg * 16 + 12];                      \
    const int mk[16] = {mA.x, mA.y, mA.z, mA.w, mB.x, mB.y, mB.z, mB.w,         \
                        mC.x, mC.y, mC.z, mC.w, mD.x, mD.y, mD.z, mD.w};        \
    float mx = -3.4e38f;                                                        \
    _Pragma("unroll")                                                           \
    for (int q = 0; q < 16; ++q) if (mk[q] > 0) mx = fmaxf(mx, CVAL[q]);        \
    _Pragma("unroll")                                                           \
    for (int sh = 1; sh < 16; sh <<= 1) mx = fmaxf(mx, __shfl_xor(mx, sh));     \
    float ev[16]; float ssum = 0.f;                                             \
    _Pragma("unroll")                                                           \
    for (int q = 0; q < 16; ++q) {                                              \
      ev[q] = (mk[q] > 0) ? __expf(CVAL[q] - mx) : 0.f; ssum += ev[q];          \
    }                                                                           \
    _Pragma("unroll")                                                           \
    for (int sh = 1; sh < 16; sh <<= 1) ssum += __shfl_xor(ssum, sh);           \
    const float inv = 1.f / ssum;                                               \
    short8 o0, o1;                                                              \
    _Pragma("unroll")                                                           \
    for (int q = 0; q < 8; ++q) {                                               \
      o0[q] = cvt_bf16(ev[q] * inv); o1[q] = cvt_bf16(ev[8 + q] * inv);         \
    }                                                                           \
    *(short8*)&AOUT[off] = o0; *(short8*)&AOUT[off + 8] = o1;                   \
    _Pragma("unroll")                                                           \
    for (int q = 0; q < 4; ++q) {                                               \
      f32x4 tv; tv[0] = CVAL[q * 4]; tv[1] = CVAL[q * 4 + 1];                   \
      tv[2] = CVAL[q * 4 + 2]; tv[3] = CVAL[q * 4 + 3];                         \
      *(f32x4*)&tile[r * 260 + seg * 16 + q * 4] = tv;                          \
    }                                                                           \
    __syncthreads();                                                            \
    {                                                                           \
      float* obase = &ONM[((long long)b * N_DIM + tid) * T_DIM + t0];           \
      _Pragma("unroll")                                                         \
      for (int g = 0; g < 4; ++g) {                                             \
        f32x4 wv;                                                               \
        wv[0] = tile[(4 * g + 0) * 260 + tid];                                  \
        wv[1] = tile[(4 * g + 1) * 260 + tid];                                  \
        wv[2] = tile[(4 * g + 2) * 260 + tid];                                  \
        wv[3] = tile[(4 * g + 3) * 260 + tid];                                  \
        *(f32x4*)&obase[4 * g] = wv;                                            \
      }                                                                         \
    }                                                                           \
    __syncthreads();                                                            \
  } while (0)

  EMIT_DOMAIN(cv, 0, Av, Onm_v);
  EMIT_DOMAIN(ct, 1, At, Onm_t);
#undef EMIT_DOMAIN
}

// ---------------------------------------------------------------------------
// Task heads
// ---------------------------------------------------------------------------
__global__ __launch_bounds__(1024)
void task_kernel(const float* __restrict__ vtask, const float* __restrict__ ttask,
                 const float* __restrict__ vtw, const float* __restrict__ vtb,
                 const float* __restrict__ ttw, const float* __restrict__ ttb,
                 float* __restrict__ out_v, float* __restrict__ out_t) {
  const int wave = threadIdx.x >> 6;
  const int lane = threadIdx.x & 63;
  const int dom = wave >> 3;
  const int b   = wave & 7;
  const float* task = dom ? ttask : vtask;
  const float* tw   = dom ? ttw : vtw;
  const float  tb   = (dom ? ttb : vtb)[0];
  float* o = dom ? out_t : out_v;
  for (int k = 0; k < NT_DIM; ++k) {
    const float* row = task + ((long long)k * B_DIM + b) * H_DIM;
    float s = 0.f;
    for (int c = lane; c < H_DIM; c += 64) s += row[c] * tw[c];
    #pragma unroll
    for (int d = 32; d > 0; d >>= 1) s += __shfl_xor(s, d);
    if (lane == 0) o[k * B_DIM + b] = s + tb;
  }
}

// ---------------------------------------------------------------------------
extern "C" void kernel_launch(void* const* d_in, const int* in_sizes, int n_in,
                              void* d_out, int out_size, void* d_ws, size_t ws_size,
                              hipStream_t stream) {
  const float* v_action = (const float*)d_in[0];
  const float* v_frame  = (const float*)d_in[1];
  const float* v_task   = (const float*)d_in[2];
  const int*   v_mask   = (const int*)d_in[3];
  const float* t_action = (const float*)d_in[4];
  const float* t_frame  = (const float*)d_in[5];
  const float* t_task   = (const float*)d_in[6];
  const int*   t_mask   = (const int*)d_in[7];
  const float* v_aw = (const float*)d_in[16];
  const float* t_aw = (const float*)d_in[17];
  const float* v_tw = (const float*)d_in[18];
  const float* v_tb = (const float*)d_in[19];
  const float* t_tw = (const float*)d_in[20];
  const float* t_tb = (const float*)d_in[21];

  const long long TBH = (long long)T_DIM * B_DIM * H_DIM;
  const long long BTN = (long long)B_DIM * T_DIM * N_DIM;
  const long long WS  = (long long)H_DIM * H_DIM;     // 262144

  float* out = (float*)d_out;
  float* out_v   = out;
  float* out_t   = out + TBH;
  float* out_vnm = out + 2 * TBH;
  float* out_tnm = out + 2 * TBH + BTN;
  float* out_vta = out + 2 * TBH + 2 * BTN;
  float* out_tta = out_vta + NT_DIM * B_DIM;

  char* w = (char*)d_ws;
  auto alloc = [&](long long bytes) {
    char* p = w; w += (bytes + 255) & ~255LL; return p;
  };
  // WT slots: 0 WQv,1 WKv,2 WVv,3 WQt,4 WKt,5 WVt (raw), 6 WoTv,7 WoTt (trans)
  short* WT    = (short*)alloc(8 * WS * 2);
  short* Mv    = (short*)alloc(WS * 2);
  short* Mt    = (short*)alloc(WS * 2);
  short* PTv   = (short*)alloc(WS * 2);
  short* PTt   = (short*)alloc(WS * 2);
  short* Ac16v = (short*)alloc(1048576LL * 2);
  short* Ac16t = (short*)alloc(1048576LL * 2);
  short* KWTv  = (short*)alloc(8LL * 131072 * 2);  // [b][n][f]
  short* KWTt  = (short*)alloc(8LL * 131072 * 2);
  short* VWTv  = (short*)alloc(8LL * 131072 * 2);  // [b][g][n]
  short* VWTt  = (short*)alloc(8LL * 131072 * 2);
  short* Av    = (short*)alloc(BTN * 2);
  short* At    = (short*)alloc(BTN * 2);
  short* Lv    = (short*)alloc(BTN * 2);
  short* Lt    = (short*)alloc(BTN * 2);

  const float rsq = 0.044194173824159216f;  // 1/sqrt(512)

  // 1. weight prep: raw cvt (Wq,Wk,Wv x2) + transposed Wo x2
  {
    W6 s6 = {{(const float*)d_in[8], (const float*)d_in[9], (const float*)d_in[10],
              (const float*)d_in[12], (const float*)d_in[13], (const float*)d_in[14]}};
    rawcvt_kernel<<<dim3(128, 6), dim3(256), 0, stream>>>(s6, WT);
    W2 s2 = {{(const float*)d_in[11], (const float*)d_in[15]}};
    wtrans_kernel<<<dim3(16, 16, 2), dim3(32, 8), 0, stream>>>(s2, WT + 6 * WS);
  }

  // 2. action -> bf16
  ac16_kernel<<<dim3(512, 2), dim3(256), 0, stream>>>(v_action, t_action, Ac16v, Ac16t);

  // 3. M = Wq@Wk^T and PT = WoT@Wv, 4 slots in one launch (z=0..3, zlog=0)
  {
    GP p = {{WT + 0 * WS, WT + 3 * WS, WT + 6 * WS, WT + 7 * WS},
            {WT + 1 * WS, WT + 4 * WS, WT + 2 * WS, WT + 5 * WS},
            {Mv, Mt, PTv, PTt},
            {nullptr, nullptr, nullptr, nullptr}};
    gemm_tn<short, short, false><<<dim3(4, 4, 4), dim3(256), 0, stream>>>(
        p, 0, 0LL, H_DIM, 0LL, H_DIM, 0LL, H_DIM, 512, 1.f);
  }

  // 4. KWT[b][n][f] = action @ M^T  (z = dom*8+b)
  {
    GP p = {{Ac16v, Ac16t}, {Mv, Mt}, {KWTv, KWTt}, {nullptr, nullptr}};
    gemm_tn<short, short, false><<<dim3(2, 4, 16), dim3(256), 0, stream>>>(
        p, 3, 512LL, B_DIM * H_DIM, 0LL, H_DIM, 131072LL, H_DIM, 512, 1.f);
  }

  // 5. VWT[b][g][n] = PT @ action^T  (z = dom*8+b)
  {
    GP p = {{PTv, PTt}, {Ac16v, Ac16t}, {VWTv, VWTt}, {nullptr, nullptr}};
    gemm_tn<short, short, false><<<dim3(4, 2, 16), dim3(256), 0, stream>>>(
        p, 3, 0LL, H_DIM, 512LL, B_DIM * H_DIM, 131072LL, N_DIM, 512, 1.f);
  }

  // 6. logits (bf16) [B,T,N] = frame @ KWT^T  (f32-A, FLAT XCD swizzle)
  {
    GP p = {{v_frame, t_frame}, {KWTv, KWTt}, {Lv, Lt}, {nullptr, nullptr}};
    gemm_tn<float, short, false, true><<<dim3(32 * 2 * 16), dim3(256), 0, stream>>>(
        p, 3, 512LL, B_DIM * H_DIM, 131072LL, H_DIM,
        (long long)T_DIM * N_DIM, N_DIM, 512, rsq, 32, 2);
  }

  // 7. fused combine + softmax + nomask-transpose
  softmax_fused<<<dim3(T_DIM / 16, B_DIM), dim3(256), 0, stream>>>(
      Lv, Lt, v_mask, t_mask, v_aw, t_aw, Av, At, out_vnm, out_tnm);

  // 8. out = attn @ VW + frame  (K=256, FLAT XCD swizzle)
  {
    GP p = {{Av, At}, {VWTv, VWTt}, {out_v, out_t}, {v_frame, t_frame}};
    gemm_tn<short, float, true, true><<<dim3(32 * 4 * 16), dim3(256), 0, stream>>>(
        p, 3, (long long)T_DIM * N_DIM, N_DIM, 131072LL, N_DIM,
        512LL, B_DIM * H_DIM, 256, 1.f, 32, 4);
  }

  // 9. task heads
  task_kernel<<<dim3(1), dim3(1024), 0, stream>>>(
      v_task, t_task, v_tw, v_tb, t_tw, t_tb, out_vta, out_tta);
}